// Round 10
// baseline (581.762 us; speedup 1.0000x reference)
//
#include <hip/hip_runtime.h>
#include <hip/hip_bf16.h>

typedef unsigned long long u64;
typedef unsigned int u32;

#define BATCH 16
#define NANCH 25200
#define NCLS 80
#define NFEAT 85
#define TOPK 1024
#define MAXDET 300
#define CONF_T 0.25f
#define IOU_T 0.45f
#define MAX_WH 7680.0f

#define GRP 16                    // anchors per wave-group
#define GRPB (GRP * NFEAT * 4)    // 5440 B, 16B-aligned
#define NGRP (NANCH / GRP)        // 1575

// async 16B global->LDS (gfx950); divergent-exec tail proven safe R0-R9.
__device__ __forceinline__ void gload_lds16(const void* g, void* l) {
    __builtin_amdgcn_global_load_lds(
        (const __attribute__((address_space(1))) unsigned int*)g,
        (__attribute__((address_space(3))) unsigned int*)l, 16, 0, 0);
}

// ---------------------------------------------------------------------------
// LDS phase union: score slices (16 waves x 5440B) | select | iou | nms.
// Max member ~138.5 KB -> 1 block/CU; grid = 256 -> all blocks co-resident
// (required for the flag spins; same residency math as R8's coop, which ran).
// ---------------------------------------------------------------------------
struct SmemS {
    u32 wcnt[16][17];
    u32 tot[17];
    u32 s_prefix12, s_cnt;
    u64 buf[2048];
};
struct SmemI { float4 sbx[TOPK]; };
struct SmemN {
    u64 sM[TOPK * 16];      // 131072
    u64 kw[16];
    int wpfx[17];
    float sdet[MAXDET * 6];
    float s_sum, s_max;
};
union SmemU { char sc[16 * GRPB]; SmemS s; SmemI i; SmemN n; };

// ---------------------------------------------------------------------------
// Phase SELECT (R9-proven verbatim): ballot-hist over the provable 18-bin
// support, >/== compaction (exact on overflow), hybrid bitonic sort,
// extraction. 1024 threads.
// ---------------------------------------------------------------------------
__device__ __forceinline__ void dev_select(int b, int tid, SmemS& sm,
                                           const u64* __restrict__ keys,
                                           const float* __restrict__ in,
                                           float4* __restrict__ box4,
                                           float4* __restrict__ boxoff4,
                                           float* __restrict__ score,
                                           float* __restrict__ cls,
                                           u64* __restrict__ vmask) {
    const int lane = tid & 63, wv = tid >> 6;
    const ulonglong2* kb2 = (const ulonglong2*)(keys + (size_t)b * NANCH);
    u64* buf = sm.buf;

    u32 myc = 0;
    for (int n = tid; n < 12600; n += 1024) {
        ulonglong2 kk = kb2[n];
        u32 b0 = (u32)(kk.x >> 52);
        u32 b1 = (u32)(kk.y >> 52);
        u32 c0 = (b0 == 0x407u) ? 16u : (b0 - 0xBE8u);
        u32 c1 = (b1 == 0x407u) ? 16u : (b1 - 0xBE8u);
#pragma unroll
        for (u32 k = 0; k < 17; ++k) {
            u64 m0 = __ballot(c0 == k);
            u64 m1 = __ballot(c1 == k);
            if (lane == (int)k) myc += (u32)__popcll(m0) + (u32)__popcll(m1);
        }
    }
    if (lane < 17) sm.wcnt[wv][lane] = myc;
    if (tid == 0) sm.s_cnt = 0u;
    __syncthreads();
    if (tid < 17) {
        u32 t = 0;
#pragma unroll
        for (int w = 0; w < 16; ++w) t += sm.wcnt[w][tid];
        sm.tot[tid] = t;
    }
    __syncthreads();
    if (tid == 0) {
        u32 acc = 0; u32 p = 0x407u;
        for (int k = 15; k >= 0; --k) {
            if (acc < (u32)TOPK && acc + sm.tot[k] >= (u32)TOPK) p = 0xBE8u + (u32)k;
            acc += sm.tot[k];
        }
        if (acc < (u32)TOPK) p = 0x407u;
        sm.s_prefix12 = p;
    }
    __syncthreads();
    const u32 p12 = sm.s_prefix12;
    for (int n = tid; n < 12600; n += 1024) {
        ulonglong2 kk = kb2[n];
        if ((u32)(kk.x >> 52) > p12) {
            u32 pos = atomicAdd(&sm.s_cnt, 1u);
            if (pos < 2048u) buf[pos] = kk.x;
        }
        if ((u32)(kk.y >> 52) > p12) {
            u32 pos = atomicAdd(&sm.s_cnt, 1u);
            if (pos < 2048u) buf[pos] = kk.y;
        }
    }
    __syncthreads();
    for (int n = tid; n < 12600; n += 1024) {
        ulonglong2 kk = kb2[n];
        if ((u32)(kk.x >> 52) == p12) {
            u32 pos = atomicAdd(&sm.s_cnt, 1u);
            if (pos < 2048u) buf[pos] = kk.x;
        }
        if ((u32)(kk.y >> 52) == p12) {
            u32 pos = atomicAdd(&sm.s_cnt, 1u);
            if (pos < 2048u) buf[pos] = kk.y;
        }
    }
    __syncthreads();
    u32 cnt = sm.s_cnt; if (cnt > 2048u) cnt = 2048u;
    for (int n = (int)cnt + tid; n < 2048; n += 1024) buf[n] = 0ull;
    __syncthreads();

    const int base = wv * 128;
    u64 r0 = buf[base + lane], r1 = buf[base + 64 + lane];
    for (int k2 = 2; k2 <= 128; k2 <<= 1) {
        const bool d0 = (((base + lane) & k2) == 0);
        const bool d1 = (((base + 64 + lane) & k2) == 0);
        for (int jj = (k2 >> 1); jj >= 1; jj >>= 1) {
            if (jj == 64) {
                u64 mx = r0 > r1 ? r0 : r1, mn = r0 > r1 ? r1 : r0;
                r0 = d0 ? mx : mn; r1 = d0 ? mn : mx;
            } else {
                const bool up = (lane & jj) != 0;
                u64 v0 = __shfl_xor(r0, jj, 64);
                u64 v1 = __shfl_xor(r1, jj, 64);
                const bool km0 = (d0 != up), km1 = (d1 != up);
                r0 = km0 ? (r0 > v0 ? r0 : v0) : (r0 < v0 ? r0 : v0);
                r1 = km1 ? (r1 > v1 ? r1 : v1) : (r1 < v1 ? r1 : v1);
            }
        }
    }
    for (int k2 = 256; k2 <= 2048; k2 <<= 1) {
        buf[base + lane] = r0; buf[base + 64 + lane] = r1;
        __syncthreads();
        for (int jj = (k2 >> 1); jj >= 128; jj >>= 1) {
            int i = ((tid & ~(jj - 1)) << 1) | (tid & (jj - 1));
            int part = i | jj;
            u64 a = buf[i], c = buf[part];
            bool sw = ((i & k2) == 0) ? (a < c) : (a > c);
            if (sw) { buf[i] = c; buf[part] = a; }
            __syncthreads();
        }
        r0 = buf[base + lane]; r1 = buf[base + 64 + lane];
        const bool d0 = (((base + lane) & k2) == 0);
        for (int jj = 64; jj >= 1; jj >>= 1) {
            if (jj == 64) {
                u64 mx = r0 > r1 ? r0 : r1, mn = r0 > r1 ? r1 : r0;
                r0 = d0 ? mx : mn; r1 = d0 ? mn : mx;
            } else {
                const bool up = (lane & jj) != 0;
                u64 v0 = __shfl_xor(r0, jj, 64);
                u64 v1 = __shfl_xor(r1, jj, 64);
                const bool km = (d0 != up);
                r0 = km ? (r0 > v0 ? r0 : v0) : (r0 < v0 ? r0 : v0);
                r1 = km ? (r1 > v1 ? r1 : v1) : (r1 < v1 ? r1 : v1);
            }
        }
    }
    buf[base + lane] = r0; buf[base + 64 + lane] = r1;
    __syncthreads();

    u64 k = buf[tid];
    u32 ord = (u32)(k >> 32);
    u32 sb = (ord & 0x80000000u) ? (ord ^ 0x80000000u) : ~ord;
    float sc = __uint_as_float(sb);
    int idx = (int)((((u32)(k >> 8)) & 0xFFFFu) ^ 0xFFFFu);
    int j = (int)(k & 0xFFu);
    const float* pr = in + ((size_t)b * NANCH + idx) * NFEAT;
    float cx = pr[0], cy = pr[1], ww = pr[2], hh = pr[3];
    float x1 = cx - ww / 2.0f, y1 = cy - hh / 2.0f;
    float x2 = cx + ww / 2.0f, y2 = cy + hh / 2.0f;
    float c = (float)j;
    float cm = c * MAX_WH;
    box4[b * TOPK + tid]    = make_float4(x1, y1, x2, y2);
    boxoff4[b * TOPK + tid] = make_float4(x1 + cm, y1 + cm, x2 + cm, y2 + cm);
    score[b * TOPK + tid] = sc;
    cls[b * TOPK + tid] = c;
    u64 bal = __ballot(sc > 0.0f);
    if ((tid & 63) == 0) vmask[b * 16 + (tid >> 6)] = bal;
}

// ---------------------------------------------------------------------------
// Phase NMS (R9-proven verbatim, stride-parameterized).
// ---------------------------------------------------------------------------
__device__ __forceinline__ void dev_nms(int b, int tid, int stride, SmemN& sm,
                                        const u64* __restrict__ M,
                                        const u64* __restrict__ vmask,
                                        const float4* __restrict__ box4,
                                        const float* __restrict__ score,
                                        const float* __restrict__ cls,
                                        float* __restrict__ out) {
    {
        const ulonglong2* Ms = (const ulonglong2*)(M + (size_t)b * TOPK * 16);
        ulonglong2* Ldst = (ulonglong2*)sm.sM;
#pragma unroll 4
        for (int t = tid; t < TOPK * 8; t += stride) Ldst[t] = Ms[t];
    }
    for (int t = tid; t < MAXDET * 6; t += stride) sm.sdet[t] = 0.0f;
    if (tid == 0) { sm.s_sum = 0.0f; sm.s_max = 0.0f; }
    __syncthreads();
    if (tid < 16) {
        const int w = tid;
        const u64 vm = vmask[b * 16 + w];
        u64 supp = ~vm;
        u64 rwA[16], rwB[16];
#pragma unroll
        for (int q = 0; q < 16; ++q) rwA[q] = sm.sM[q * 16 + w];
        for (int wb = 0; wb < 16; ++wb) {
            u64 cur = __shfl(supp, wb, 64);
#pragma unroll
            for (int c4 = 0; c4 < 4; ++c4) {
                const int rn = wb * 64 + (c4 + 1) * 16;
                if (rn < 1024) {
#pragma unroll
                    for (int q = 0; q < 16; ++q) rwB[q] = sm.sM[(rn + q) * 16 + w];
                }
                u64 rc[16];
#pragma unroll
                for (int q = 0; q < 16; ++q) rc[q] = __shfl(rwA[q], wb, 64);
                u64 ar0 = rc[0] | rc[4] | rc[8]  | rc[12];
                u64 ar1 = rc[1] | rc[5] | rc[9]  | rc[13];
                u64 ar2 = rc[2] | rc[6] | rc[10] | rc[14];
                u64 ar3 = rc[3] | rc[7] | rc[11] | rc[15];
                const u32 intra = (u32)(((ar0 | ar1) | (ar2 | ar3)) >> (c4 * 16)) & 0xFFFFu;
                const u32 actm  = (~(u32)(cur >> (c4 * 16))) & 0xFFFFu;
                if (intra == 0u || actm == 0u) {
                    u64 s0 = 0, s1 = 0, s2 = 0, s3 = 0;
                    u64 c0 = 0, c1 = 0, c2 = 0, c3 = 0;
#pragma unroll
                    for (int q = 0; q < 16; q += 4) {
                        const u64 m0 = ((actm >> (q + 0)) & 1u) ? ~0ull : 0ull;
                        const u64 m1 = ((actm >> (q + 1)) & 1u) ? ~0ull : 0ull;
                        const u64 m2 = ((actm >> (q + 2)) & 1u) ? ~0ull : 0ull;
                        const u64 m3 = ((actm >> (q + 3)) & 1u) ? ~0ull : 0ull;
                        s0 |= rwA[q + 0] & m0;  c0 |= rc[q + 0] & m0;
                        s1 |= rwA[q + 1] & m1;  c1 |= rc[q + 1] & m1;
                        s2 |= rwA[q + 2] & m2;  c2 |= rc[q + 2] & m2;
                        s3 |= rwA[q + 3] & m3;  c3 |= rc[q + 3] & m3;
                    }
                    supp |= (s0 | s1) | (s2 | s3);
                    cur  |= (c0 | c1) | (c2 | c3);
                } else {
#pragma unroll
                    for (int q = 0; q < 16; ++q) {
                        const int ii = c4 * 16 + q;
                        const bool act = ((cur >> ii) & 1ull) == 0ull;
                        supp = act ? (supp | rwA[q]) : supp;
                        cur  = act ? (cur  | rc[q])  : cur;
                    }
                }
#pragma unroll
                for (int q = 0; q < 16; ++q) rwA[q] = rwB[q];
            }
        }
        sm.kw[w] = vm & ~supp;
    }
    __syncthreads();
    if (tid == 0) {
        int acc = 0;
        for (int w = 0; w < 16; ++w) { sm.wpfx[w] = acc; acc += __popcll(sm.kw[w]); }
        sm.wpfx[16] = acc;
    }
    __syncthreads();
    for (int r = tid; r < TOPK; r += stride) {
        int w = r >> 6, bp = r & 63;
        if ((sm.kw[w] >> bp) & 1ull) {
            int pos = sm.wpfx[w] + __popcll(sm.kw[w] & ((1ull << bp) - 1ull));
            if (pos < MAXDET) {
                float4 bx = box4[b * TOPK + r];
                float s = score[b * TOPK + r];
                float c = cls[b * TOPK + r];
                sm.sdet[pos * 6 + 0] = bx.x;
                sm.sdet[pos * 6 + 1] = bx.y;
                sm.sdet[pos * 6 + 2] = bx.z;
                sm.sdet[pos * 6 + 3] = bx.w;
                sm.sdet[pos * 6 + 4] = s;
                sm.sdet[pos * 6 + 5] = c;
                float term = (fabsf(bx.x - bx.z) + fabsf(bx.y - bx.w)) * s;
                atomicAdd(&sm.s_sum, term);
                if (pos == 0) sm.s_max = s;
            }
        }
    }
    __syncthreads();
    if (tid == 0) {
        int n = sm.wpfx[16]; if (n > MAXDET) n = MAXDET;
        float wh = (n > 0) ? (sm.s_sum / (2.0f * (float)n)) : 0.0f;
        atomicAdd(&out[0], sm.s_max / (float)BATCH);
        atomicAdd(&out[1], wh / (float)BATCH);
    }
    if (b == 2) {
        for (int t = tid; t < MAXDET * 6; t += stride) out[2 + t] = sm.sdet[t];
    }
}

// ---------------------------------------------------------------------------
// MEGA persistent pipeline. 256 blocks x 1024 thr, 1 block/CU (LDS-forced),
// all co-resident. Point-to-point flag waits (device atomics + threadfence,
// the Guideline-16 pattern; protocol correctness proven by R8's passing coop
// run). Fences are per-block per-phase (~500 total), not per-wave.
//   flags: done_cnt[16] (score, ==16), sel_done[16] (==1), iou_done[16] (==16)
// ---------------------------------------------------------------------------
__global__ __launch_bounds__(1024) void mega(const float* __restrict__ in,
                                             u64* __restrict__ keys,
                                             float4* __restrict__ box4,
                                             float4* __restrict__ boxoff4,
                                             float* __restrict__ score,
                                             float* __restrict__ cls,
                                             u64* __restrict__ vmask,
                                             u64* __restrict__ M,
                                             u32* __restrict__ flags,
                                             float* __restrict__ out) {
    __shared__ SmemU u;
    const int B = blockIdx.x, tid = threadIdx.x;
    const int wv = tid >> 6, lane = tid & 63;
    u32* done_cnt = flags;        // [16]
    u32* sel_done = flags + 16;   // [16]
    u32* iou_done = flags + 32;   // [16]

    if (B == 0 && tid == 0) {     // atomic stores: coherent vs later RMWs
        atomicExch((u32*)&out[0], 0u);
        atomicExch((u32*)&out[1], 0u);
    }

    // ================= phase SCORE (all 256 blocks) =================
    {
        char* myl = u.sc + wv * GRPB;                  // 16 slices x 5440B
        const float* myp = (const float*)myl + (lane >> 2) * NFEAT;
        const int a = lane >> 2, q = lane & 3;
        const int batch = B >> 4;                      // 16 blocks per batch
        const int wid8 = ((B & 15) << 4) | wv;         // 0..255 within batch
        for (int g = wid8; g < NGRP; g += 256) {       // 6-7 groups/wave
            const int a0 = g * GRP;
            const char* gbase = (const char*)(in + ((size_t)batch * NANCH + a0) * NFEAT);
#pragma unroll
            for (int r = 0; r < 6; ++r) {
                const int myb = (r << 10) + lane * 16;
                if (myb < GRPB) gload_lds16(gbase + myb, myl + (r << 10));
            }
            asm volatile("s_waitcnt vmcnt(0)" ::: "memory");
            __builtin_amdgcn_sched_barrier(0);
            float obj = myp[4];
            float best = -1e30f;
            int bj = 0;
#pragma unroll
            for (int k = 0; k < 20; ++k) {
                float v = myp[5 + q * 20 + k] * obj;
                if (v > best) { best = v; bj = q * 20 + k; }
            }
#pragma unroll
            for (int d = 1; d < 4; d <<= 1) {
                float ob = __shfl_xor(best, d, 64);
                int oj = __shfl_xor(bj, d, 64);
                if (ob > best || (ob == best && oj < bj)) { best = ob; bj = oj; }
            }
            if (q == 0) {
                bool valid = (obj > CONF_T) && (best > CONF_T);
                float sc = valid ? best : -1.0f;
                u32 sb = __float_as_uint(sc);
                u32 ord = sb ^ ((sb & 0x80000000u) ? 0xFFFFFFFFu : 0x80000000u);
                int idx = a0 + a;
                keys[(size_t)batch * NANCH + idx] =
                    ((u64)ord << 32) | ((u64)((u32)(idx ^ 0xFFFF) & 0xFFFFu) << 8) | (u64)bj;
            }
            // wave-private LDS slice: next-iter DMA overwrite is safe, all
            // ds_reads of this slice are consumed above (in-order per wave).
        }
        __threadfence();                // release keys (all threads)
        __syncthreads();                // block's score done
        if (tid == 0) atomicAdd(&done_cnt[batch], 1u);
    }

    // ================= phase SELECT (blocks 0..15) =================
    if (B < BATCH) {
        if (tid == 0)
            while (atomicAdd(&done_cnt[B], 0u) < 16u) __builtin_amdgcn_s_sleep(32);
        __syncthreads();
        __threadfence();                // acquire keys
        dev_select(B, tid, u.s, keys, in, box4, boxoff4, score, cls, vmask);
        __threadfence();                // release boxoff4/box4/score/cls/vmask
        __syncthreads();
        if (tid == 0) atomicAdd(&sel_done[B], 1u);
    }

    // ================= phase IOU (one 64-row unit per block) =================
    {
        const int unit = (B >= BATCH) ? (B - BATCH) : (240 + B);
        const int ub = unit >> 4, quad = unit & 15;    // batch, row-stripe
        if (tid == 0)
            while (atomicAdd(&sel_done[ub], 0u) < 1u) __builtin_amdgcn_s_sleep(32);
        __syncthreads();
        __threadfence();                // acquire boxoff4
        const int jmin = quad << 6;
        for (int t = jmin + tid; t < TOPK; t += 1024) u.i.sbx[t] = boxoff4[ub * TOPK + t];
        __syncthreads();
#pragma unroll
        for (int s = 0; s < 4; ++s) {
            const int i = (quad << 6) | (wv << 2) | s;
            const float4 A = u.i.sbx[i];
            const float areaA = (A.z - A.x) * (A.w - A.y);
            u64 myword = 0ull;
            for (int t = quad; t < 16; ++t) {
                int j = (t << 6) | lane;
                float4 Bx = u.i.sbx[j];
                float lx = fmaxf(A.x, Bx.x), ly = fmaxf(A.y, Bx.y);
                float rx = fminf(A.z, Bx.z), ry = fminf(A.w, Bx.w);
                float iw = fmaxf(rx - lx, 0.0f), ih = fmaxf(ry - ly, 0.0f);
                float inter = iw * ih;
                float areaB = (Bx.z - Bx.x) * (Bx.w - Bx.y);
                float iou = inter / (areaA + areaB - inter + 1e-7f);
                bool pred = (iou > IOU_T) && (j > i);
                u64 bal = __ballot(pred);
                if (lane == t) myword = bal;
            }
            if (lane < 16) M[((size_t)ub * TOPK + i) * 16 + lane] = myword;
        }
        __threadfence();                // release M rows
        __syncthreads();
        if (tid == 0) atomicAdd(&iou_done[ub], 1u);
    }

    // ================= phase NMS (blocks 0..15) =================
    if (B < BATCH) {
        if (tid == 0)
            while (atomicAdd(&iou_done[B], 0u) < 16u) __builtin_amdgcn_s_sleep(32);
        __syncthreads();
        __threadfence();                // acquire M
        dev_nms(B, tid, 1024, u.n, M, vmask, box4, score, cls, out);
    }
}

extern "C" void kernel_launch(void* const* d_in, const int* in_sizes, int n_in,
                              void* d_out, int out_size, void* d_ws, size_t ws_size,
                              hipStream_t stream) {
    const float* in = (const float*)d_in[0];
    float* out = (float*)d_out;
    char* ws = (char*)d_ws;

    u64*    keys     = (u64*)   (ws + 0);                       // 3,225,600
    float4* boxoff4  = (float4*)(ws + 3225600);                 //   262,144
    float4* box4     = (float4*)(ws + 3487744);                 //   262,144
    float*  score    = (float*) (ws + 3749888);                 //    65,536
    float*  cls      = (float*) (ws + 3815424);                 //    65,536
    u64*    vmask    = (u64*)   (ws + 3880960);                 //     2,048
    u64*    M        = (u64*)   (ws + 3883008);                 // 2,097,152
    u32*    flags    = (u32*)   (ws + 5980160);                 //       192

    hipMemsetAsync(flags, 0, 192, stream);   // capturable (harness fills too)
    mega<<<256, 1024, 0, stream>>>(in, keys, box4, boxoff4, score, cls, vmask,
                                   M, flags, out);
}